// Round 2
// baseline (31907.886 us; speedup 1.0000x reference)
//
#include <hip/hip_runtime.h>
#include <hip/hip_bf16.h>

#define SEQ 8192
#define HID 2048
#define NBLK 64        // persistent scan blocks (<= 256 CUs -> co-resident)
#define ROWS 32        // Wh rows per block (NBLK*ROWS == HID)

typedef short short8 __attribute__((ext_vector_type(8)));
typedef float floatx4 __attribute__((ext_vector_type(4)));

// Split 8 consecutive f32 into bf16 hi + bf16 lo fragments (RNE rounding).
// x == hi + lo to ~2^-16 relative.
__device__ __forceinline__ void split_bf16(const float* __restrict__ p,
                                           short8& hi, short8& lo) {
    const float4 f0 = *(const float4*)p;
    const float4 f1 = *(const float4*)(p + 4);
    const float f[8] = {f0.x, f0.y, f0.z, f0.w, f1.x, f1.y, f1.z, f1.w};
#pragma unroll
    for (int e = 0; e < 8; ++e) {
        const unsigned u = __float_as_uint(f[e]);
        const unsigned r = (u + 0x7fffu + ((u >> 16) & 1u)) & 0xffff0000u;
        hi[e] = (short)(r >> 16);
        const float l = f[e] - __uint_as_float(r);
        const unsigned ul = __float_as_uint(l);
        lo[e] = (short)((ul + 0x7fffu + ((ul >> 16) & 1u)) >> 16);
    }
}

// ---------------------------------------------------------------------------
// Kernel 1: xp[s,h] = sum_k x[s,k]*Wi[h,k] + bi[h]  (f32 in, f32 out)
// bf16-split MFMA: 3 products per k-chunk, error ~1e-4 abs.
// 64x64 block tile, 4 waves in 2x2, each wave 32x32 via 2x2 of 16x16x32 MFMA.
// ---------------------------------------------------------------------------
__global__ __launch_bounds__(256) void xproj_gemm(
    const float* __restrict__ x,       // [SEQ, HID]
    const float* __restrict__ Wi,      // [HID, HID] (row = out feature)
    const float* __restrict__ bi,      // [HID]
    float* __restrict__ xp)            // [SEQ, HID]
{
    const int bn = blockIdx.x;          // N tile (HID/64)
    const int bm = blockIdx.y;          // M tile (SEQ/64)
    const int tid = threadIdx.x;
    const int wave = tid >> 6;
    const int lane = tid & 63;
    const int wM = wave & 1, wN = wave >> 1;
    const int l16 = lane & 15, kq = lane >> 4;   // A/B frag: idx=l16, k=kq*8+j
    const int m0 = bm * 64 + wM * 32;
    const int n0 = bn * 64 + wN * 32;

    floatx4 acc00 = {0.f,0.f,0.f,0.f}, acc01 = {0.f,0.f,0.f,0.f};
    floatx4 acc10 = {0.f,0.f,0.f,0.f}, acc11 = {0.f,0.f,0.f,0.f};

    const float* xA0 = x  + (size_t)(m0 + l16)      * HID;
    const float* xA1 = x  + (size_t)(m0 + 16 + l16) * HID;
    const float* wB0 = Wi + (size_t)(n0 + l16)      * HID;
    const float* wB1 = Wi + (size_t)(n0 + 16 + l16) * HID;

    for (int kc = 0; kc < HID; kc += 32) {
        const int k = kc + kq * 8;
        short8 a0h, a0l, a1h, a1l, b0h, b0l, b1h, b1l;
        split_bf16(xA0 + k, a0h, a0l);
        split_bf16(xA1 + k, a1h, a1l);
        split_bf16(wB0 + k, b0h, b0l);
        split_bf16(wB1 + k, b1h, b1l);
        // acc += Ahi*Bhi + Alo*Bhi + Ahi*Blo  (drop lo*lo, ~2^-16 rel)
        acc00 = __builtin_amdgcn_mfma_f32_16x16x32_bf16(a0h, b0h, acc00, 0,0,0);
        acc00 = __builtin_amdgcn_mfma_f32_16x16x32_bf16(a0l, b0h, acc00, 0,0,0);
        acc00 = __builtin_amdgcn_mfma_f32_16x16x32_bf16(a0h, b0l, acc00, 0,0,0);
        acc01 = __builtin_amdgcn_mfma_f32_16x16x32_bf16(a0h, b1h, acc01, 0,0,0);
        acc01 = __builtin_amdgcn_mfma_f32_16x16x32_bf16(a0l, b1h, acc01, 0,0,0);
        acc01 = __builtin_amdgcn_mfma_f32_16x16x32_bf16(a0h, b1l, acc01, 0,0,0);
        acc10 = __builtin_amdgcn_mfma_f32_16x16x32_bf16(a1h, b0h, acc10, 0,0,0);
        acc10 = __builtin_amdgcn_mfma_f32_16x16x32_bf16(a1l, b0h, acc10, 0,0,0);
        acc10 = __builtin_amdgcn_mfma_f32_16x16x32_bf16(a1h, b0l, acc10, 0,0,0);
        acc11 = __builtin_amdgcn_mfma_f32_16x16x32_bf16(a1h, b1h, acc11, 0,0,0);
        acc11 = __builtin_amdgcn_mfma_f32_16x16x32_bf16(a1l, b1h, acc11, 0,0,0);
        acc11 = __builtin_amdgcn_mfma_f32_16x16x32_bf16(a1h, b1l, acc11, 0,0,0);
    }

    // C/D layout: col = lane&15, row = (lane>>4)*4 + reg   [m89-verified]
    const float bi0 = bi[n0 + l16];
    const float bi1 = bi[n0 + 16 + l16];
#pragma unroll
    for (int reg = 0; reg < 4; ++reg) {
        const int mlo = m0 + kq * 4 + reg;
        const int mhi = mlo + 16;
        xp[(size_t)mlo * HID + n0 + l16]      = acc00[reg] + bi0;
        xp[(size_t)mlo * HID + n0 + 16 + l16] = acc01[reg] + bi1;
        xp[(size_t)mhi * HID + n0 + l16]      = acc10[reg] + bi0;
        xp[(size_t)mhi * HID + n0 + 16 + l16] = acc11[reg] + bi1;
    }
}

// ---------------------------------------------------------------------------
// Kernel 2: persistent recurrence. 64 blocks x 512 threads. Block b owns rows
// [b*32, b*32+32) of Wh in VGPRs (f32). Per step: poll 64 producer flags
// (epoch = step), stage h_{t-1} (f32, double-buffered) into LDS via
// agent-scope loads, dot, 64-lane butterfly reduce, tanh, agent-scope store
// of this block's 32 h values, drain, flag publish (release).
// Flags start at 0xAAAAAAAA (harness ws poison) == negative int -> not ready.
// ---------------------------------------------------------------------------
__global__ __launch_bounds__(512, 1) void rnn_scan(
    const float* __restrict__ Wh,    // [HID, HID]
    const float* __restrict__ bh,    // [HID]
    const float* __restrict__ xp,    // [SEQ, HID]
    float* hbuf,                     // [2, HID] exchange
    int* flags,                      // [NBLK]
    float* out)                      // [SEQ*HID + HID]
{
    __shared__ float h_lds[HID];

    const int b   = blockIdx.x;
    const int tid = threadIdx.x;
    const int wv  = tid >> 6;    // wave = row group (4 rows each)
    const int L   = tid & 63;

    // --- one-time: Wh rows -> registers. Lane L covers cols 256*j+4*L+{0..3}.
    float w[4][8][4];
#pragma unroll
    for (int r = 0; r < 4; ++r) {
        const size_t row = (size_t)(b * ROWS + wv * 4 + r);
#pragma unroll
        for (int j = 0; j < 8; ++j) {
            const float4 pk = *(const float4*)(Wh + row * HID + 256 * j + 4 * L);
            w[r][j][0] = pk.x; w[r][j][1] = pk.y;
            w[r][j][2] = pk.z; w[r][j][3] = pk.w;
        }
    }
    const float bh_l = (L < 4) ? bh[b * ROWS + wv * 4 + L] : 0.f;

    for (int t = 0; t < SEQ; ++t) {
        // prefetch this step's x_proj for the 4 writer lanes (hidden by poll)
        float xp_l = 0.f;
        if (L < 4) xp_l = xp[(size_t)t * HID + b * ROWS + wv * 4 + L];

        float acc[4] = {0.f, 0.f, 0.f, 0.f};

        if (t > 0) {
            // poll: wave 0, lane i watches producer i
            if (tid < NBLK) {
                while (__hip_atomic_load(&flags[tid], __ATOMIC_RELAXED,
                                         __HIP_MEMORY_SCOPE_AGENT) < t) { }
            }
            __syncthreads();
            // stage h_{t-1} (buffer (t-1)&1) into LDS; agent loads bypass L1/L2
            const unsigned long long* hb =
                (const unsigned long long*)(hbuf + ((t & 1) ^ 1) * HID);
#pragma unroll
            for (int q = 0; q < 2; ++q) {
                const int idx = tid + 512 * q;   // 1024 u64 = 2048 f32
                unsigned long long v = __hip_atomic_load(hb + idx, __ATOMIC_RELAXED,
                                                         __HIP_MEMORY_SCOPE_AGENT);
                ((unsigned long long*)h_lds)[idx] = v;
            }
            __syncthreads();
            // dot: 4 rows x 32 cols per lane
#pragma unroll
            for (int j = 0; j < 8; ++j) {
                const float4 hv = *(const float4*)&h_lds[256 * j + 4 * L];
#pragma unroll
                for (int r = 0; r < 4; ++r) {
                    acc[r] += w[r][j][0] * hv.x;
                    acc[r] += w[r][j][1] * hv.y;
                    acc[r] += w[r][j][2] * hv.z;
                    acc[r] += w[r][j][3] * hv.w;
                }
            }
        }

        // 64-lane butterfly reduce (every lane ends with full row sums)
#pragma unroll
        for (int off = 32; off > 0; off >>= 1) {
#pragma unroll
            for (int r = 0; r < 4; ++r) acc[r] += __shfl_xor(acc[r], off, 64);
        }

        if (L < 4) {
            const int row = b * ROWS + wv * 4 + L;
            const float a = acc[L] + xp_l + bh_l;
            const float hval = tanhf(a);
            __hip_atomic_store(&hbuf[(t & 1) * HID + row], hval,
                               __ATOMIC_RELAXED, __HIP_MEMORY_SCOPE_AGENT);
            out[(size_t)t * HID + row] = hval;
            if (t == SEQ - 1)
                out[(size_t)SEQ * HID + row] = hval;
        }
        // drain stores before publishing the epoch
        asm volatile("s_waitcnt vmcnt(0)" ::: "memory");
        __syncthreads();
        if (tid == 0)
            __hip_atomic_store(&flags[b], t + 1,
                               __ATOMIC_RELEASE, __HIP_MEMORY_SCOPE_AGENT);
    }
}

// ---------------------------------------------------------------------------
extern "C" void kernel_launch(void* const* d_in, const int* in_sizes, int n_in,
                              void* d_out, int out_size, void* d_ws, size_t ws_size,
                              hipStream_t stream) {
    const float* x  = (const float*)d_in[0];   // [8192,2048] f32
    const float* Wi = (const float*)d_in[1];   // [2048,2048] f32
    const float* bi = (const float*)d_in[2];   // [2048] f32
    const float* Wh = (const float*)d_in[3];   // [2048,2048] f32
    const float* bh = (const float*)d_in[4];   // [2048] f32
    float* out      = (float*)d_out;           // outputs [8192,2048] ++ h_n [2048]

    // ws layout: xp f32 [SEQ*HID] (64 MB) | hbuf f32 [2*HID] | flags int [NBLK]
    float* xp    = (float*)d_ws;
    float* hbuf  = xp + (size_t)SEQ * HID;
    int*   flags = (int*)(hbuf + 2 * HID);

    xproj_gemm<<<dim3(HID / 64, SEQ / 64), 256, 0, stream>>>(x, Wi, bi, xp);
    rnn_scan<<<NBLK, 512, 0, stream>>>(Wh, bh, xp, hbuf, flags, out);
}

// Round 3
// 23679.604 us; speedup vs baseline: 1.3475x; 1.3475x over previous
//
#include <hip/hip_runtime.h>
#include <hip/hip_bf16.h>

#define SEQ 8192
#define HID 2048
#define NBLK 64        // persistent scan blocks (<= 256 CUs -> co-resident)
#define ROWS 32        // Wh rows per block (NBLK*ROWS == HID)

typedef short short8 __attribute__((ext_vector_type(8)));
typedef float floatx4 __attribute__((ext_vector_type(4)));

// Split 8 consecutive f32 into bf16 hi + bf16 lo fragments (RNE rounding).
__device__ __forceinline__ void split_bf16(const float* __restrict__ p,
                                           short8& hi, short8& lo) {
    const float4 f0 = *(const float4*)p;
    const float4 f1 = *(const float4*)(p + 4);
    const float f[8] = {f0.x, f0.y, f0.z, f0.w, f1.x, f1.y, f1.z, f1.w};
#pragma unroll
    for (int e = 0; e < 8; ++e) {
        const unsigned u = __float_as_uint(f[e]);
        const unsigned r = (u + 0x7fffu + ((u >> 16) & 1u)) & 0xffff0000u;
        hi[e] = (short)(r >> 16);
        const float l = f[e] - __uint_as_float(r);
        const unsigned ul = __float_as_uint(l);
        lo[e] = (short)((ul + 0x7fffu + ((ul >> 16) & 1u)) >> 16);
    }
}

// ---------------------------------------------------------------------------
// Kernel 1: xp[s,h] = sum_k x[s,k]*Wi[h,k] + bi[h]  (f32 in/out, bf16-split
// MFMA: 3 products per k-chunk, ~1e-4 abs error).
// ---------------------------------------------------------------------------
__global__ __launch_bounds__(256) void xproj_gemm(
    const float* __restrict__ x,       // [SEQ, HID]
    const float* __restrict__ Wi,      // [HID, HID]
    const float* __restrict__ bi,      // [HID]
    float* __restrict__ xp)            // [SEQ, HID]
{
    const int bn = blockIdx.x;
    const int bm = blockIdx.y;
    const int tid = threadIdx.x;
    const int wave = tid >> 6;
    const int lane = tid & 63;
    const int wM = wave & 1, wN = wave >> 1;
    const int l16 = lane & 15, kq = lane >> 4;
    const int m0 = bm * 64 + wM * 32;
    const int n0 = bn * 64 + wN * 32;

    floatx4 acc00 = {0.f,0.f,0.f,0.f}, acc01 = {0.f,0.f,0.f,0.f};
    floatx4 acc10 = {0.f,0.f,0.f,0.f}, acc11 = {0.f,0.f,0.f,0.f};

    const float* xA0 = x  + (size_t)(m0 + l16)      * HID;
    const float* xA1 = x  + (size_t)(m0 + 16 + l16) * HID;
    const float* wB0 = Wi + (size_t)(n0 + l16)      * HID;
    const float* wB1 = Wi + (size_t)(n0 + 16 + l16) * HID;

    for (int kc = 0; kc < HID; kc += 32) {
        const int k = kc + kq * 8;
        short8 a0h, a0l, a1h, a1l, b0h, b0l, b1h, b1l;
        split_bf16(xA0 + k, a0h, a0l);
        split_bf16(xA1 + k, a1h, a1l);
        split_bf16(wB0 + k, b0h, b0l);
        split_bf16(wB1 + k, b1h, b1l);
        acc00 = __builtin_amdgcn_mfma_f32_16x16x32_bf16(a0h, b0h, acc00, 0,0,0);
        acc00 = __builtin_amdgcn_mfma_f32_16x16x32_bf16(a0l, b0h, acc00, 0,0,0);
        acc00 = __builtin_amdgcn_mfma_f32_16x16x32_bf16(a0h, b0l, acc00, 0,0,0);
        acc01 = __builtin_amdgcn_mfma_f32_16x16x32_bf16(a0h, b1h, acc01, 0,0,0);
        acc01 = __builtin_amdgcn_mfma_f32_16x16x32_bf16(a0l, b1h, acc01, 0,0,0);
        acc01 = __builtin_amdgcn_mfma_f32_16x16x32_bf16(a0h, b1l, acc01, 0,0,0);
        acc10 = __builtin_amdgcn_mfma_f32_16x16x32_bf16(a1h, b0h, acc10, 0,0,0);
        acc10 = __builtin_amdgcn_mfma_f32_16x16x32_bf16(a1l, b0h, acc10, 0,0,0);
        acc10 = __builtin_amdgcn_mfma_f32_16x16x32_bf16(a1h, b0l, acc10, 0,0,0);
        acc11 = __builtin_amdgcn_mfma_f32_16x16x32_bf16(a1h, b1h, acc11, 0,0,0);
        acc11 = __builtin_amdgcn_mfma_f32_16x16x32_bf16(a1l, b1h, acc11, 0,0,0);
        acc11 = __builtin_amdgcn_mfma_f32_16x16x32_bf16(a1h, b1l, acc11, 0,0,0);
    }

    const float bi0 = bi[n0 + l16];
    const float bi1 = bi[n0 + 16 + l16];
#pragma unroll
    for (int reg = 0; reg < 4; ++reg) {
        const int mlo = m0 + kq * 4 + reg;
        const int mhi = mlo + 16;
        xp[(size_t)mlo * HID + n0 + l16]      = acc00[reg] + bi0;
        xp[(size_t)mlo * HID + n0 + 16 + l16] = acc01[reg] + bi1;
        xp[(size_t)mhi * HID + n0 + l16]      = acc10[reg] + bi0;
        xp[(size_t)mhi * HID + n0 + 16 + l16] = acc11[reg] + bi1;
    }
}

// ---------------------------------------------------------------------------
// Kernel 2: persistent recurrence with ONE-HOP tagged-data exchange.
// hbuf slot = u64 { hi: epoch, lo: f32 bits }. Producer's store IS the
// publication (no flags, no vmcnt drain). Consumer polls the 4 slots it
// stages into LDS until tag == t-1. Double buffer by step parity; tag
// equality + the all-to-all data dependency of the dot make overwrite
// races and LDS WAR across steps impossible (see round-3 analysis).
// ws poison 0xAA... gives tag 0xAAAAAAAA = negative int -> never matches.
// ---------------------------------------------------------------------------
__global__ __launch_bounds__(512, 1) void rnn_scan(
    const float* __restrict__ Wh,    // [HID, HID]
    const float* __restrict__ bh,    // [HID]
    const float* __restrict__ xp,    // [SEQ, HID]
    unsigned long long* hbuf,        // [2][HID] tagged exchange
    float* out)                      // [SEQ*HID + HID]
{
    __shared__ float h_lds[HID];

    const int b   = blockIdx.x;
    const int tid = threadIdx.x;
    const int wv  = tid >> 6;    // wave = row group (4 rows each)
    const int L   = tid & 63;

    // one-time: Wh rows -> registers. Lane L covers cols 256*j+4*L+{0..3}.
    float w[4][8][4];
#pragma unroll
    for (int r = 0; r < 4; ++r) {
        const size_t row = (size_t)(b * ROWS + wv * 4 + r);
#pragma unroll
        for (int j = 0; j < 8; ++j) {
            const float4 pk = *(const float4*)(Wh + row * HID + 256 * j + 4 * L);
            w[r][j][0] = pk.x; w[r][j][1] = pk.y;
            w[r][j][2] = pk.z; w[r][j][3] = pk.w;
        }
    }
    const float bh_l = (L < 4) ? bh[b * ROWS + wv * 4 + L] : 0.f;

    for (int t = 0; t < SEQ; ++t) {
        // independent prefetch of this step's x_proj (hidden by the poll)
        float xp_l = 0.f;
        if (L < 4) xp_l = xp[(size_t)t * HID + b * ROWS + wv * 4 + L];

        float acc[4] = {0.f, 0.f, 0.f, 0.f};

        if (t > 0) {
            const unsigned long long* src = hbuf + ((t - 1) & 1) * HID;
            const int want = t - 1;
            // poll + stage: thread tid owns slots [4*tid, 4*tid+4)
#pragma unroll
            for (int q = 0; q < 4; ++q) {
                const int idx = 4 * tid + q;
                unsigned long long v;
                do {
                    v = __hip_atomic_load(src + idx, __ATOMIC_RELAXED,
                                          __HIP_MEMORY_SCOPE_AGENT);
                } while ((int)(v >> 32) != want);
                h_lds[idx] = __uint_as_float((unsigned)v);
            }
            __syncthreads();   // the ONLY barrier per step
            // dot: 4 rows x 32 cols per lane
#pragma unroll
            for (int j = 0; j < 8; ++j) {
                const float4 hv = *(const float4*)&h_lds[256 * j + 4 * L];
#pragma unroll
                for (int r = 0; r < 4; ++r) {
                    acc[r] += w[r][j][0] * hv.x;
                    acc[r] += w[r][j][1] * hv.y;
                    acc[r] += w[r][j][2] * hv.z;
                    acc[r] += w[r][j][3] * hv.w;
                }
            }
        }

        // 64-lane butterfly reduce (every lane ends with full row sums)
#pragma unroll
        for (int off = 32; off > 0; off >>= 1) {
#pragma unroll
            for (int r = 0; r < 4; ++r) acc[r] += __shfl_xor(acc[r], off, 64);
        }

        if (L < 4) {
            const int row = b * ROWS + wv * 4 + L;
            float a = acc[L] + xp_l + bh_l;
            // fast tanh via hw exp: (e^2a - 1)/(e^2a + 1), clamped (no inf/nan)
            a = fminf(fmaxf(a, -15.f), 15.f);
            const float e = __expf(2.f * a);
            const float hval = (e - 1.f) / (e + 1.f);
            const unsigned long long tagged =
                ((unsigned long long)(unsigned)t << 32) |
                (unsigned long long)__float_as_uint(hval);
            __hip_atomic_store(&hbuf[(t & 1) * HID + row], tagged,
                               __ATOMIC_RELAXED, __HIP_MEMORY_SCOPE_AGENT);
            out[(size_t)t * HID + row] = hval;
            if (t == SEQ - 1)
                out[(size_t)SEQ * HID + row] = hval;
        }
        // no drain, no end barrier: tag chain orders everything
    }
}

// ---------------------------------------------------------------------------
extern "C" void kernel_launch(void* const* d_in, const int* in_sizes, int n_in,
                              void* d_out, int out_size, void* d_ws, size_t ws_size,
                              hipStream_t stream) {
    const float* x  = (const float*)d_in[0];   // [8192,2048] f32
    const float* Wi = (const float*)d_in[1];   // [2048,2048] f32
    const float* bi = (const float*)d_in[2];   // [2048] f32
    const float* Wh = (const float*)d_in[3];   // [2048,2048] f32
    const float* bh = (const float*)d_in[4];   // [2048] f32
    float* out      = (float*)d_out;           // outputs ++ h_n

    // ws: xp f32 [SEQ*HID] (64 MB) | hbuf u64 [2*HID] (32 KB)
    float* xp = (float*)d_ws;
    unsigned long long* hbuf = (unsigned long long*)(xp + (size_t)SEQ * HID);

    xproj_gemm<<<dim3(HID / 64, SEQ / 64), 256, 0, stream>>>(x, Wi, bi, xp);
    rnn_scan<<<NBLK, 512, 0, stream>>>(Wh, bh, xp, hbuf, out);
}

// Round 4
// 20917.789 us; speedup vs baseline: 1.5254x; 1.1320x over previous
//
#include <hip/hip_runtime.h>
#include <hip/hip_bf16.h>

#define SEQ 8192
#define HID 2048
#define NBLK 64        // persistent scan blocks (distinct CUs -> co-resident)
#define ROWS 32        // Wh rows per block (NBLK*ROWS == HID)

typedef short short8 __attribute__((ext_vector_type(8)));
typedef float floatx4 __attribute__((ext_vector_type(4)));

// Split 8 consecutive f32 into bf16 hi + bf16 lo fragments (RNE rounding).
__device__ __forceinline__ void split_bf16(const float* __restrict__ p,
                                           short8& hi, short8& lo) {
    const float4 f0 = *(const float4*)p;
    const float4 f1 = *(const float4*)(p + 4);
    const float f[8] = {f0.x, f0.y, f0.z, f0.w, f1.x, f1.y, f1.z, f1.w};
#pragma unroll
    for (int e = 0; e < 8; ++e) {
        const unsigned u = __float_as_uint(f[e]);
        const unsigned r = (u + 0x7fffu + ((u >> 16) & 1u)) & 0xffff0000u;
        hi[e] = (short)(r >> 16);
        const float l = f[e] - __uint_as_float(r);
        const unsigned ul = __float_as_uint(l);
        lo[e] = (short)((ul + 0x7fffu + ((ul >> 16) & 1u)) >> 16);
    }
}

// ---------------------------------------------------------------------------
// Kernel 1: xp[s,h] = sum_k x[s,k]*Wi[h,k] + bi[h]  (f32 in/out, bf16-split
// MFMA: 3 products per k-chunk, ~1e-4 abs error).
// ---------------------------------------------------------------------------
__global__ __launch_bounds__(256) void xproj_gemm(
    const float* __restrict__ x,       // [SEQ, HID]
    const float* __restrict__ Wi,      // [HID, HID]
    const float* __restrict__ bi,      // [HID]
    float* __restrict__ xp)            // [SEQ, HID]
{
    const int bn = blockIdx.x;
    const int bm = blockIdx.y;
    const int tid = threadIdx.x;
    const int wave = tid >> 6;
    const int lane = tid & 63;
    const int wM = wave & 1, wN = wave >> 1;
    const int l16 = lane & 15, kq = lane >> 4;
    const int m0 = bm * 64 + wM * 32;
    const int n0 = bn * 64 + wN * 32;

    floatx4 acc00 = {0.f,0.f,0.f,0.f}, acc01 = {0.f,0.f,0.f,0.f};
    floatx4 acc10 = {0.f,0.f,0.f,0.f}, acc11 = {0.f,0.f,0.f,0.f};

    const float* xA0 = x  + (size_t)(m0 + l16)      * HID;
    const float* xA1 = x  + (size_t)(m0 + 16 + l16) * HID;
    const float* wB0 = Wi + (size_t)(n0 + l16)      * HID;
    const float* wB1 = Wi + (size_t)(n0 + 16 + l16) * HID;

    for (int kc = 0; kc < HID; kc += 32) {
        const int k = kc + kq * 8;
        short8 a0h, a0l, a1h, a1l, b0h, b0l, b1h, b1l;
        split_bf16(xA0 + k, a0h, a0l);
        split_bf16(xA1 + k, a1h, a1l);
        split_bf16(wB0 + k, b0h, b0l);
        split_bf16(wB1 + k, b1h, b1l);
        acc00 = __builtin_amdgcn_mfma_f32_16x16x32_bf16(a0h, b0h, acc00, 0,0,0);
        acc00 = __builtin_amdgcn_mfma_f32_16x16x32_bf16(a0l, b0h, acc00, 0,0,0);
        acc00 = __builtin_amdgcn_mfma_f32_16x16x32_bf16(a0h, b0l, acc00, 0,0,0);
        acc01 = __builtin_amdgcn_mfma_f32_16x16x32_bf16(a0h, b1h, acc01, 0,0,0);
        acc01 = __builtin_amdgcn_mfma_f32_16x16x32_bf16(a0l, b1h, acc01, 0,0,0);
        acc01 = __builtin_amdgcn_mfma_f32_16x16x32_bf16(a0h, b1l, acc01, 0,0,0);
        acc10 = __builtin_amdgcn_mfma_f32_16x16x32_bf16(a1h, b0h, acc10, 0,0,0);
        acc10 = __builtin_amdgcn_mfma_f32_16x16x32_bf16(a1l, b0h, acc10, 0,0,0);
        acc10 = __builtin_amdgcn_mfma_f32_16x16x32_bf16(a1h, b0l, acc10, 0,0,0);
        acc11 = __builtin_amdgcn_mfma_f32_16x16x32_bf16(a1h, b1h, acc11, 0,0,0);
        acc11 = __builtin_amdgcn_mfma_f32_16x16x32_bf16(a1l, b1h, acc11, 0,0,0);
        acc11 = __builtin_amdgcn_mfma_f32_16x16x32_bf16(a1h, b1l, acc11, 0,0,0);
    }

    const float bi0 = bi[n0 + l16];
    const float bi1 = bi[n0 + 16 + l16];
#pragma unroll
    for (int reg = 0; reg < 4; ++reg) {
        const int mlo = m0 + kq * 4 + reg;
        const int mhi = mlo + 16;
        xp[(size_t)mlo * HID + n0 + l16]      = acc00[reg] + bi0;
        xp[(size_t)mlo * HID + n0 + 16 + l16] = acc01[reg] + bi1;
        xp[(size_t)mhi * HID + n0 + l16]      = acc10[reg] + bi0;
        xp[(size_t)mhi * HID + n0 + 16 + l16] = acc11[reg] + bi1;
    }
}

// ---------------------------------------------------------------------------
// Kernel 2: persistent recurrence, one-hop tagged-data exchange.
// hbuf slot = u64 { hi: epoch, lo: f32 bits }; store IS the publication.
// Round-4 fixes: (a) the 4 per-thread polls issue CONCURRENTLY (one
// round-trip per retry round, not four); (b) slot ownership tid+512*q so a
// wave's poll load is 512B contiguous (coalesced, 8 lines not 32);
// (c) LDS staging h_lds[tid+512*q] -> bank tid%32, 2-way (free).
// Safety: tag-equality + all-to-all dependency of the dot orders everything
// (a block can only reach its step-t+1 LDS writes after every producer's
// step-t store, which data-depends on that producer's step-t LDS reads).
// ws poison 0xAAAAAAAA can never equal a tag in [0, SEQ).
// ---------------------------------------------------------------------------
__global__ __launch_bounds__(512, 1) void rnn_scan(
    const float* __restrict__ Wh,    // [HID, HID]
    const float* __restrict__ bh,    // [HID]
    const float* __restrict__ xp,    // [SEQ, HID]
    unsigned long long* hbuf,        // [2][HID] tagged exchange
    float* out)                      // [SEQ*HID + HID]
{
    __shared__ float h_lds[HID];

    const int b   = blockIdx.x;
    const int tid = threadIdx.x;
    const int wv  = tid >> 6;    // wave = row group (4 rows each)
    const int L   = tid & 63;

    // one-time: Wh rows -> registers. Lane L covers cols 256*j+4*L+{0..3}.
    floatx4 w[4][8];
#pragma unroll
    for (int r = 0; r < 4; ++r) {
        const size_t row = (size_t)(b * ROWS + wv * 4 + r);
#pragma unroll
        for (int j = 0; j < 8; ++j)
            w[r][j] = *(const floatx4*)(Wh + row * HID + 256 * j + 4 * L);
    }
    const float bh_l = (L < 4) ? bh[b * ROWS + wv * 4 + L] : 0.f;

    for (int t = 0; t < SEQ; ++t) {
        // independent prefetch of this step's x_proj (hidden by the poll)
        float xp_l = 0.f;
        if (L < 4) xp_l = xp[(size_t)t * HID + b * ROWS + wv * 4 + L];

        float acc[4] = {0.f, 0.f, 0.f, 0.f};

        if (t > 0) {
            const unsigned long long* src = hbuf + ((t - 1) & 1) * HID;
            const unsigned want = (unsigned)(t - 1);
            unsigned long long v0, v1, v2, v3;
            do {   // 4 loads in flight per retry round: ONE round-trip
                v0 = __hip_atomic_load(src + tid,        __ATOMIC_RELAXED,
                                       __HIP_MEMORY_SCOPE_AGENT);
                v1 = __hip_atomic_load(src + tid + 512,  __ATOMIC_RELAXED,
                                       __HIP_MEMORY_SCOPE_AGENT);
                v2 = __hip_atomic_load(src + tid + 1024, __ATOMIC_RELAXED,
                                       __HIP_MEMORY_SCOPE_AGENT);
                v3 = __hip_atomic_load(src + tid + 1536, __ATOMIC_RELAXED,
                                       __HIP_MEMORY_SCOPE_AGENT);
            } while (((unsigned)(v0 >> 32) != want) |
                     ((unsigned)(v1 >> 32) != want) |
                     ((unsigned)(v2 >> 32) != want) |
                     ((unsigned)(v3 >> 32) != want));
            h_lds[tid]        = __uint_as_float((unsigned)v0);
            h_lds[tid + 512]  = __uint_as_float((unsigned)v1);
            h_lds[tid + 1024] = __uint_as_float((unsigned)v2);
            h_lds[tid + 1536] = __uint_as_float((unsigned)v3);
            __syncthreads();   // the ONLY barrier per step
            // dot: 4 rows x 32 cols per lane (b128 reads, conflict-free)
#pragma unroll
            for (int j = 0; j < 8; ++j) {
                const float4 hv = *(const float4*)&h_lds[256 * j + 4 * L];
#pragma unroll
                for (int r = 0; r < 4; ++r) {
                    acc[r] += w[r][j][0] * hv.x;
                    acc[r] += w[r][j][1] * hv.y;
                    acc[r] += w[r][j][2] * hv.z;
                    acc[r] += w[r][j][3] * hv.w;
                }
            }
        }

        // 64-lane butterfly reduce (every lane ends with full row sums)
#pragma unroll
        for (int off = 32; off > 0; off >>= 1) {
#pragma unroll
            for (int r = 0; r < 4; ++r) acc[r] += __shfl_xor(acc[r], off, 64);
        }

        if (L < 4) {
            const int row = b * ROWS + wv * 4 + L;
            float a = acc[L] + xp_l + bh_l;
            // fast tanh via hw exp: (e^2a - 1)/(e^2a + 1), clamped
            a = fminf(fmaxf(a, -15.f), 15.f);
            const float e = __expf(2.f * a);
            const float hval = (e - 1.f) / (e + 1.f);
            const unsigned long long tagged =
                ((unsigned long long)(unsigned)t << 32) |
                (unsigned long long)__float_as_uint(hval);
            __hip_atomic_store(&hbuf[(t & 1) * HID + row], tagged,
                               __ATOMIC_RELAXED, __HIP_MEMORY_SCOPE_AGENT);
            out[(size_t)t * HID + row] = hval;
            if (t == SEQ - 1)
                out[(size_t)SEQ * HID + row] = hval;
        }
        // no drain, no end barrier: the tag chain orders everything
    }
}

// ---------------------------------------------------------------------------
extern "C" void kernel_launch(void* const* d_in, const int* in_sizes, int n_in,
                              void* d_out, int out_size, void* d_ws, size_t ws_size,
                              hipStream_t stream) {
    const float* x  = (const float*)d_in[0];   // [8192,2048] f32
    const float* Wi = (const float*)d_in[1];   // [2048,2048] f32
    const float* bi = (const float*)d_in[2];   // [2048] f32
    const float* Wh = (const float*)d_in[3];   // [2048,2048] f32
    const float* bh = (const float*)d_in[4];   // [2048] f32
    float* out      = (float*)d_out;           // outputs ++ h_n

    // ws: xp f32 [SEQ*HID] (64 MB) | hbuf u64 [2*HID] (32 KB)
    float* xp = (float*)d_ws;
    unsigned long long* hbuf = (unsigned long long*)(xp + (size_t)SEQ * HID);

    xproj_gemm<<<dim3(HID / 64, SEQ / 64), 256, 0, stream>>>(x, Wi, bi, xp);
    rnn_scan<<<NBLK, 512, 0, stream>>>(Wh, bh, xp, hbuf, out);
}

// Round 5
// 20611.865 us; speedup vs baseline: 1.5480x; 1.0148x over previous
//
#include <hip/hip_runtime.h>
#include <hip/hip_bf16.h>

#define SEQ 8192
#define HID 2048
#define NBLK 64        // persistent scan blocks (distinct CUs -> co-resident)
#define ROWS 32        // Wh rows per block (NBLK*ROWS == HID)

typedef short short8 __attribute__((ext_vector_type(8)));
typedef float floatx4 __attribute__((ext_vector_type(4)));
typedef unsigned uintx4 __attribute__((ext_vector_type(4)));

// Split 8 consecutive f32 into bf16 hi + bf16 lo fragments (RNE rounding).
__device__ __forceinline__ void split_bf16(const float* __restrict__ p,
                                           short8& hi, short8& lo) {
    const float4 f0 = *(const float4*)p;
    const float4 f1 = *(const float4*)(p + 4);
    const float f[8] = {f0.x, f0.y, f0.z, f0.w, f1.x, f1.y, f1.z, f1.w};
#pragma unroll
    for (int e = 0; e < 8; ++e) {
        const unsigned u = __float_as_uint(f[e]);
        const unsigned r = (u + 0x7fffu + ((u >> 16) & 1u)) & 0xffff0000u;
        hi[e] = (short)(r >> 16);
        const float l = f[e] - __uint_as_float(r);
        const unsigned ul = __float_as_uint(l);
        lo[e] = (short)((ul + 0x7fffu + ((ul >> 16) & 1u)) >> 16);
    }
}

// ---------------------------------------------------------------------------
// Kernel 1: xp[s,h] = sum_k x[s,k]*Wi[h,k] + bi[h]  (f32 in/out, bf16-split
// MFMA: 3 products per k-chunk, ~1e-4 abs error).
// ---------------------------------------------------------------------------
__global__ __launch_bounds__(256) void xproj_gemm(
    const float* __restrict__ x,       // [SEQ, HID]
    const float* __restrict__ Wi,      // [HID, HID]
    const float* __restrict__ bi,      // [HID]
    float* __restrict__ xp)            // [SEQ, HID]
{
    const int bn = blockIdx.x;
    const int bm = blockIdx.y;
    const int tid = threadIdx.x;
    const int wave = tid >> 6;
    const int lane = tid & 63;
    const int wM = wave & 1, wN = wave >> 1;
    const int l16 = lane & 15, kq = lane >> 4;
    const int m0 = bm * 64 + wM * 32;
    const int n0 = bn * 64 + wN * 32;

    floatx4 acc00 = {0.f,0.f,0.f,0.f}, acc01 = {0.f,0.f,0.f,0.f};
    floatx4 acc10 = {0.f,0.f,0.f,0.f}, acc11 = {0.f,0.f,0.f,0.f};

    const float* xA0 = x  + (size_t)(m0 + l16)      * HID;
    const float* xA1 = x  + (size_t)(m0 + 16 + l16) * HID;
    const float* wB0 = Wi + (size_t)(n0 + l16)      * HID;
    const float* wB1 = Wi + (size_t)(n0 + 16 + l16) * HID;

    for (int kc = 0; kc < HID; kc += 32) {
        const int k = kc + kq * 8;
        short8 a0h, a0l, a1h, a1l, b0h, b0l, b1h, b1l;
        split_bf16(xA0 + k, a0h, a0l);
        split_bf16(xA1 + k, a1h, a1l);
        split_bf16(wB0 + k, b0h, b0l);
        split_bf16(wB1 + k, b1h, b1l);
        acc00 = __builtin_amdgcn_mfma_f32_16x16x32_bf16(a0h, b0h, acc00, 0,0,0);
        acc00 = __builtin_amdgcn_mfma_f32_16x16x32_bf16(a0l, b0h, acc00, 0,0,0);
        acc00 = __builtin_amdgcn_mfma_f32_16x16x32_bf16(a0h, b0l, acc00, 0,0,0);
        acc01 = __builtin_amdgcn_mfma_f32_16x16x32_bf16(a0h, b1h, acc01, 0,0,0);
        acc01 = __builtin_amdgcn_mfma_f32_16x16x32_bf16(a0l, b1h, acc01, 0,0,0);
        acc01 = __builtin_amdgcn_mfma_f32_16x16x32_bf16(a0h, b1l, acc01, 0,0,0);
        acc10 = __builtin_amdgcn_mfma_f32_16x16x32_bf16(a1h, b0h, acc10, 0,0,0);
        acc10 = __builtin_amdgcn_mfma_f32_16x16x32_bf16(a1l, b0h, acc10, 0,0,0);
        acc10 = __builtin_amdgcn_mfma_f32_16x16x32_bf16(a1h, b0l, acc10, 0,0,0);
        acc11 = __builtin_amdgcn_mfma_f32_16x16x32_bf16(a1h, b1h, acc11, 0,0,0);
        acc11 = __builtin_amdgcn_mfma_f32_16x16x32_bf16(a1l, b1h, acc11, 0,0,0);
        acc11 = __builtin_amdgcn_mfma_f32_16x16x32_bf16(a1h, b1l, acc11, 0,0,0);
    }

    const float bi0 = bi[n0 + l16];
    const float bi1 = bi[n0 + 16 + l16];
#pragma unroll
    for (int reg = 0; reg < 4; ++reg) {
        const int mlo = m0 + kq * 4 + reg;
        const int mhi = mlo + 16;
        xp[(size_t)mlo * HID + n0 + l16]      = acc00[reg] + bi0;
        xp[(size_t)mlo * HID + n0 + 16 + l16] = acc01[reg] + bi1;
        xp[(size_t)mhi * HID + n0 + l16]      = acc10[reg] + bi0;
        xp[(size_t)mhi * HID + n0 + 16 + l16] = acc11[reg] + bi1;
    }
}

// ---------------------------------------------------------------------------
// Kernel 2: persistent recurrence, one-hop tagged-data exchange.
// Round-5 structure:
//  - poll = 2x global_load_dwordx4 sc0 sc1 per thread (dense 1KB/wave/instr,
//    128 line-transactions per block-round vs 2048 8B atomics)
//  - LDS-only barrier (s_waitcnt lgkmcnt(0); s_barrier): global stores stay
//    in flight across the step boundary (no vmcnt(0) drain -> no HBM-ack
//    on the critical path)
//  - out[] store for step t-1 issued at step t post-detect (fully hidden)
//  - xp prefetched one step ahead
// Safety: tag chain orders everything. A wave's step-t hbuf store data-
// depends on its step-t LDS reads; step-t+1 staging polls ALL slots (incl.
// own block's rows), so all waves' reads are complete before any LDS write.
// Buffer-parity reuse is safe: tag t overwrites tag t-2 only after every
// block stored t-1, which implies every block finished polling t-2.
// ws poison 0xAAAAAAAA never equals a tag in [0, SEQ).
// ---------------------------------------------------------------------------
__global__ __launch_bounds__(512, 1) void rnn_scan(
    const float* __restrict__ Wh,    // [HID, HID]
    const float* __restrict__ bh,    // [HID]
    const float* __restrict__ xp,    // [SEQ, HID]
    unsigned long long* hbuf,        // [2][HID] tagged exchange
    float* out)                      // [SEQ*HID + HID]
{
    __shared__ float h_lds[HID];

    const int b   = blockIdx.x;
    const int tid = threadIdx.x;
    const int wv  = tid >> 6;        // wave = row group (4 rows each)
    const int L   = tid & 63;
    const int row = b * ROWS + wv * 4 + L;   // meaningful when L < 4

    // one-time: Wh rows -> registers. Lane L covers cols 256*j+4*L+{0..3}.
    floatx4 w[4][8];
#pragma unroll
    for (int r = 0; r < 4; ++r) {
        const size_t rr = (size_t)(b * ROWS + wv * 4 + r);
#pragma unroll
        for (int j = 0; j < 8; ++j)
            w[r][j] = *(const floatx4*)(Wh + rr * HID + 256 * j + 4 * L);
    }
    const float bh_l = (L < 4) ? bh[row] : 0.f;

    float xp_cur = (L < 4) ? xp[row] : 0.f;   // step 0
    float prev_h = 0.f;

    for (int t = 0; t < SEQ; ++t) {
        float acc[4] = {0.f, 0.f, 0.f, 0.f};

        if (t > 0) {
            const unsigned long long* src = hbuf + ((t - 1) & 1) * HID;
            const unsigned want = (unsigned)(t - 1);
            const unsigned long long* s0 = src + 2 * tid;
            const unsigned long long* s1 = src + 1024 + 2 * tid;
            uintx4 p0, p1;   // [data, tag, data, tag]
            do {   // one round-trip per retry round; wide + coalesced
                asm volatile(
                    "global_load_dwordx4 %0, %2, off sc0 sc1\n\t"
                    "global_load_dwordx4 %1, %3, off sc0 sc1\n\t"
                    "s_waitcnt vmcnt(0)"
                    : "=&v"(p0), "=&v"(p1)
                    : "v"(s0), "v"(s1)
                    : "memory");
            } while ((p0[1] != want) | (p0[3] != want) |
                     (p1[1] != want) | (p1[3] != want));
            *(float2*)&h_lds[2 * tid] =
                make_float2(__uint_as_float(p0[0]), __uint_as_float(p0[2]));
            *(float2*)&h_lds[1024 + 2 * tid] =
                make_float2(__uint_as_float(p1[0]), __uint_as_float(p1[2]));
            // deferred out[] store for step t-1: ~1800cy to retire unseen
            if (L < 4) out[(size_t)(t - 1) * HID + row] = prev_h;
            // LDS-only barrier: do NOT drain vmcnt (stores stay in flight)
            asm volatile("s_waitcnt lgkmcnt(0)\n\ts_barrier" ::: "memory");
        }

        // prefetch next step's xp (used next iteration; fully hidden)
        float xp_next = 0.f;
        if (L < 4 && t + 1 < SEQ) xp_next = xp[(size_t)(t + 1) * HID + row];

        if (t > 0) {
            // dot: 4 rows x 32 cols per lane (b128 LDS reads, conflict-free)
#pragma unroll
            for (int j = 0; j < 8; ++j) {
                const float4 hv = *(const float4*)&h_lds[256 * j + 4 * L];
#pragma unroll
                for (int r = 0; r < 4; ++r) {
                    acc[r] += w[r][j][0] * hv.x;
                    acc[r] += w[r][j][1] * hv.y;
                    acc[r] += w[r][j][2] * hv.z;
                    acc[r] += w[r][j][3] * hv.w;
                }
            }
        }

        // 64-lane butterfly reduce
#pragma unroll
        for (int off = 32; off > 0; off >>= 1) {
#pragma unroll
            for (int r = 0; r < 4; ++r) acc[r] += __shfl_xor(acc[r], off, 64);
        }

        if (L < 4) {
            float a = acc[L] + xp_cur + bh_l;
            a = fminf(fmaxf(a, -15.f), 15.f);
            const float e = __expf(2.f * a);
            const float hval = (e - 1.f) / (e + 1.f);
            const unsigned long long tagged =
                ((unsigned long long)(unsigned)t << 32) |
                (unsigned long long)__float_as_uint(hval);
            __hip_atomic_store(&hbuf[(t & 1) * HID + row], tagged,
                               __ATOMIC_RELAXED, __HIP_MEMORY_SCOPE_AGENT);
            prev_h = hval;
        }
        xp_cur = xp_next;
    }

    if (L < 4) {
        out[(size_t)(SEQ - 1) * HID + row] = prev_h;   // last step's output
        out[(size_t)SEQ * HID + row]       = prev_h;   // h_n
    }
}

// ---------------------------------------------------------------------------
extern "C" void kernel_launch(void* const* d_in, const int* in_sizes, int n_in,
                              void* d_out, int out_size, void* d_ws, size_t ws_size,
                              hipStream_t stream) {
    const float* x  = (const float*)d_in[0];   // [8192,2048] f32
    const float* Wi = (const float*)d_in[1];   // [2048,2048] f32
    const float* bi = (const float*)d_in[2];   // [2048] f32
    const float* Wh = (const float*)d_in[3];   // [2048,2048] f32
    const float* bh = (const float*)d_in[4];   // [2048] f32
    float* out      = (float*)d_out;           // outputs ++ h_n

    // ws: xp f32 [SEQ*HID] (64 MB) | hbuf u64 [2*HID] (32 KB)
    float* xp = (float*)d_ws;
    unsigned long long* hbuf = (unsigned long long*)(xp + (size_t)SEQ * HID);

    xproj_gemm<<<dim3(HID / 64, SEQ / 64), 256, 0, stream>>>(x, Wi, bi, xp);
    rnn_scan<<<NBLK, 512, 0, stream>>>(Wh, bh, xp, hbuf, out);
}